// Round 1
// baseline (13961.800 us; speedup 1.0000x reference)
//
#include <hip/hip_runtime.h>
#include <hip/hip_bf16.h>

#define B_ 128
#define T_ 2048
#define D_ 128
#define H_ 512
#define L_ 10
#define NG 8      // batch groups
#define GB 16     // batches per group (MFMA N)
#define NS 16     // gate-slice workgroups per group
#define HS 32     // hidden units per slice
#define KTOT 640  // K = 512 (h) + 128 (x)
#define NKK 20    // K-steps of 32

typedef __attribute__((ext_vector_type(8))) short short8;
typedef __attribute__((ext_vector_type(4))) float f32x4;

__device__ __forceinline__ unsigned short f2bf(float f) {
    union { float f; unsigned u; } v; v.f = f;
    unsigned r = v.u + 0x7fffu + ((v.u >> 16) & 1u);
    return (unsigned short)(r >> 16);
}

// Persistent LSTM kernel. Grid = 128 blocks = 8 groups x 16 slices.
// blockIdx: g = blockIdx & 7 (so a group's WGs land round-robin on one XCD
// under the usual dispatch; correctness does not depend on it), s = blockIdx >> 3.
// Weights live in VGPRs as MFMA A-fragments for the whole kernel.
__global__ __launch_bounds__(512, 2) void lstm_kernel(
    const float* __restrict__ x, const float* __restrict__ W_ih,
    const float* __restrict__ W_hh, const float* __restrict__ bias,
    unsigned short* __restrict__ h_buf,   // [2][128][512] bf16
    unsigned int* __restrict__ arrive,    // [T+1][8]
    float* __restrict__ hfin)             // [128][512] fp32
{
    const int g    = blockIdx.x & 7;
    const int s    = blockIdx.x >> 3;
    const int tid  = threadIdx.x;
    const int lane = tid & 63;
    const int w    = tid >> 6;     // wave 0..7
    const int q    = w >> 1;       // gate (i,f,g,o)
    const int half = w & 1;        // which 16 of the 32 hidden units

    __shared__ short Bstage[NKK * 64 * 8];          // 20480 B, fragment-order
    __shared__ float gate_lds[4][HS][GB + 1];       // +1 pad vs bank conflicts

    // ---- one-time: load weight A-fragments into VGPRs (bf16) ----
    // A[m = lane&15][k = (lane>>4)*8 + j]; row r = q*512 + s*32 + half*16 + m
    short8 wfrag[NKK];
    {
        const int m    = lane & 15;
        const int quad = lane >> 4;
        const int r    = q * 512 + s * HS + half * 16 + m;
        #pragma unroll
        for (int kk = 0; kk < NKK; ++kk) {
            const int k0 = kk * 32 + quad * 8;
            short8 v;
            #pragma unroll
            for (int j = 0; j < 8; ++j) {
                const int k = k0 + j;
                const float f = (k < 512) ? W_hh[r * 512 + k]
                                          : W_ih[r * 128 + (k - 512)];
                v[j] = (short)f2bf(f);
            }
            wfrag[kk] = v;
        }
    }

    // ---- elementwise-phase mapping: one (hidden unit, batch) per thread ----
    const int e_n  = tid & 15;          // batch within group
    const int e_hu = tid >> 4;          // 0..31 hidden within slice
    const int hu_g = s * HS + e_hu;     // global hidden unit
    const int bb   = g * GB + e_n;      // global batch
    const float bi = bias[0 * 512 + hu_g];
    const float bf = bias[1 * 512 + hu_g];
    const float bg = bias[2 * 512 + hu_g];
    const float bo = bias[3 * 512 + hu_g];
    float c_val = 0.f;

    for (int t = 0; t < T_; ++t) {
        // ---- wait until all 16 slices published h_t ----
        if (t > 0) {
            if (tid == 0) {
                while (__hip_atomic_load(&arrive[t * 8 + g], __ATOMIC_RELAXED,
                                         __HIP_MEMORY_SCOPE_AGENT) < NS)
                    __builtin_amdgcn_s_sleep(1);
                (void)__hip_atomic_load(&arrive[t * 8 + g], __ATOMIC_ACQUIRE,
                                        __HIP_MEMORY_SCOPE_AGENT);
            }
            __syncthreads();
        }

        // ---- stage B fragments: B[k][n] = (k<512 ? h_t[n][k] : x[n][t][k-512]) ----
        const unsigned short* hsrc = h_buf + (size_t)(t & 1) * (B_ * H_);
        for (int c = tid; c < NKK * 64; c += 512) {
            const int kk = c >> 6;
            const int ln = c & 63;
            const int n  = ln & 15;
            const int k0 = kk * 32 + (ln >> 4) * 8;
            short8 v;
            if (k0 < 512) {
                v = *(const short8*)(hsrc + (size_t)(g * GB + n) * H_ + k0);
            } else {
                const float* xp = x + ((size_t)(g * GB + n) * T_ + t) * D_ + (k0 - 512);
                #pragma unroll
                for (int j = 0; j < 8; ++j) v[j] = (short)f2bf(xp[j]);
            }
            *(short8*)&Bstage[c * 8] = v;
        }
        __syncthreads();

        // ---- MFMA: 16x16 tile per wave, K = 640 ----
        f32x4 acc = {0.f, 0.f, 0.f, 0.f};
        #pragma unroll
        for (int kk = 0; kk < NKK; ++kk) {
            const short8 bfr = *(const short8*)&Bstage[(kk * 64 + lane) * 8];
            acc = __builtin_amdgcn_mfma_f32_16x16x32_bf16(wfrag[kk], bfr, acc, 0, 0, 0);
        }
        // D layout: col = lane&15, row = (lane>>4)*4 + reg
        {
            const int col  = lane & 15;
            const int quad = lane >> 4;
            #pragma unroll
            for (int rr = 0; rr < 4; ++rr)
                gate_lds[q][half * 16 + quad * 4 + rr][col] = acc[rr];
        }
        __syncthreads();

        // ---- elementwise LSTM cell (fp32 c in registers) ----
        {
            const float gi = gate_lds[0][e_hu][e_n] + bi;
            const float gf = gate_lds[1][e_hu][e_n] + bf;
            const float gg = gate_lds[2][e_hu][e_n] + bg;
            const float go = gate_lds[3][e_hu][e_n] + bo;
            const float si = 1.f / (1.f + __expf(-gi));
            const float sf = 1.f / (1.f + __expf(-gf));
            const float so = 1.f / (1.f + __expf(-go));
            const float tg = tanhf(gg);
            c_val = sf * c_val + si * tg;
            const float h = so * tanhf(c_val);
            unsigned short* hdst = h_buf + (size_t)((t + 1) & 1) * (B_ * H_);
            hdst[(size_t)bb * H_ + hu_g] = f2bf(h);
            if (t == T_ - 1) hfin[(size_t)bb * H_ + hu_g] = h;
        }
        __syncthreads();   // all h stores drained (vmcnt(0) before s_barrier)

        // ---- publish h_{t+1} (agent-scope release flushes L2) ----
        if (tid == 0)
            __hip_atomic_fetch_add(&arrive[(t + 1) * 8 + g], 1u, __ATOMIC_RELEASE,
                                   __HIP_MEMORY_SCOPE_AGENT);
    }
}

// Head: logits = h_final @ W_out^T, softmax. One wave per batch row.
__global__ void head_kernel(const float* __restrict__ hfin,
                            const float* __restrict__ W_out,
                            float* __restrict__ out)
{
    const int bidx = blockIdx.x;
    const int l    = threadIdx.x;      // 0..63
    float hv[8];
    #pragma unroll
    for (int j = 0; j < 8; ++j) hv[j] = hfin[bidx * 512 + j * 64 + l];
    __shared__ float logits[L_];
    for (int o = 0; o < L_; ++o) {
        float p = 0.f;
        #pragma unroll
        for (int j = 0; j < 8; ++j) p += hv[j] * W_out[o * 512 + j * 64 + l];
        #pragma unroll
        for (int off = 32; off; off >>= 1) p += __shfl_down(p, off, 64);
        if (l == 0) logits[o] = p;
    }
    __syncthreads();
    if (l == 0) {
        float mx = logits[0];
        for (int o = 1; o < L_; ++o) mx = fmaxf(mx, logits[o]);
        float e[L_], sum = 0.f;
        for (int o = 0; o < L_; ++o) { e[o] = __expf(logits[o] - mx); sum += e[o]; }
        const float inv = 1.f / sum;
        for (int o = 0; o < L_; ++o) out[bidx * L_ + o] = e[o] * inv;
    }
}

extern "C" void kernel_launch(void* const* d_in, const int* in_sizes, int n_in,
                              void* d_out, int out_size, void* d_ws, size_t ws_size,
                              hipStream_t stream) {
    const float* x     = (const float*)d_in[0];
    const float* W_ih  = (const float*)d_in[1];
    const float* W_hh  = (const float*)d_in[2];
    const float* bias  = (const float*)d_in[3];
    const float* W_out = (const float*)d_in[4];
    float* out = (float*)d_out;

    // ws layout: h_buf [2][128][512] bf16 (262144 B) | arrive [2049][8] u32
    // (65792 B incl pad) | hfin [128][512] f32 (262144 B). Total ~590 KB.
    char* ws = (char*)d_ws;
    unsigned short* h_buf  = (unsigned short*)ws;
    unsigned int*   arrive = (unsigned int*)(ws + 262144);
    float*          hfin   = (float*)(ws + 262144 + 65792);

    // zero h0 and the arrival flags (ws is poisoned 0xAA before every launch)
    hipMemsetAsync(ws, 0, 262144 + 65792, stream);

    void* args[] = { (void*)&x, (void*)&W_ih, (void*)&W_hh, (void*)&bias,
                     (void*)&h_buf, (void*)&arrive, (void*)&hfin };
    hipLaunchCooperativeKernel((void*)lstm_kernel, dim3(NG * NS), dim3(512),
                               args, 0, stream);
    head_kernel<<<dim3(B_), dim3(64), 0, stream>>>(hfin, W_out, out);
}

// Round 2
// 7889.664 us; speedup vs baseline: 1.7696x; 1.7696x over previous
//
#include <hip/hip_runtime.h>
#include <hip/hip_bf16.h>

#define B_ 128
#define T_ 2048
#define D_ 128
#define H_ 512
#define L_ 10
#define NG 8      // batch groups
#define GB 16     // batches per group (MFMA N)
#define NS 16     // gate-slice workgroups per group
#define HS 32     // hidden units per slice
#define NKK 20    // K-steps of 32 (16 h-steps + 4 x-steps)

typedef __attribute__((ext_vector_type(8))) short short8;
typedef __attribute__((ext_vector_type(4))) float f32x4;

__device__ __forceinline__ unsigned short f2bf(float f) {
    union { float f; unsigned u; } v; v.f = f;
    unsigned r = v.u + 0x7fffu + ((v.u >> 16) & 1u);
    return (unsigned short)(r >> 16);
}
__device__ __forceinline__ float fast_sig(float x) {
    return 1.f / (1.f + __expf(-x));
}
__device__ __forceinline__ float fast_tanh(float x) {
    // 1 - 2/(e^{2x}+1); exp overflow -> inf -> 1-0 = 1 (correct saturation)
    return 1.f - 2.f / (__expf(2.f * x) + 1.f);
}

// Persistent LSTM. Grid = 128 = 8 groups x 16 slices. Weights in VGPRs as
// MFMA A-fragments. Cross-WG h exchange via RELAXED agent-scope u32 atomics
// (write-through to device coherence point; NO acquire/release fences ->
// no per-step buffer_inv/buffer_wbl2 L2 nukes, which cost R1 ~5 us/step).
__global__ __launch_bounds__(512, 2) void lstm_kernel(
    const float* __restrict__ x, const float* __restrict__ W_ih,
    const float* __restrict__ W_hh, const float* __restrict__ bias,
    unsigned int* h_buf,          // [2][128][256] u32 (bf16 pairs)
    unsigned int* arrive,         // [T+1][8]
    float* __restrict__ hfin)     // [128][512] fp32
{
    const int g    = blockIdx.x & 7;
    const int s    = blockIdx.x >> 3;
    const int tid  = threadIdx.x;
    const int lane = tid & 63;
    const int w    = tid >> 6;     // wave 0..7
    const int q    = w >> 1;       // gate (i,f,g,o)
    const int half = w & 1;        // which 16 of the 32 hidden units

    __shared__ short Bstage[NKK * 64 * 8];          // 20480 B, fragment-order
    __shared__ float gate_lds[4][HS][GB + 1];       // +1 pad

    // ---- one-time: weight A-fragments in VGPRs (bf16), K = [h(512) | x(128)] ----
    short8 wfrag[NKK];
    {
        const int m    = lane & 15;
        const int quad = lane >> 4;
        const int r    = q * 512 + s * HS + half * 16 + m;
        #pragma unroll
        for (int kk = 0; kk < NKK; ++kk) {
            const int k0 = kk * 32 + quad * 8;
            short8 v;
            #pragma unroll
            for (int j = 0; j < 8; ++j) {
                const int k = k0 + j;
                const float f = (k < 512) ? W_hh[r * 512 + k]
                                          : W_ih[r * 128 + (k - 512)];
                v[j] = (short)f2bf(f);
            }
            wfrag[kk] = v;
        }
    }

    // ---- elementwise mapping: one (hidden unit, batch) per thread ----
    const int e_n  = tid & 15;
    const int e_hu = tid >> 4;          // 0..31
    const int hu_g = s * HS + e_hu;
    const int bb   = g * GB + e_n;
    const float bi = bias[0 * 512 + hu_g];
    const float bf = bias[1 * 512 + hu_g];
    const float bg = bias[2 * 512 + hu_g];
    const float bo = bias[3 * 512 + hu_g];
    float c_val = 0.f;

    for (int t = 0; t < T_; ++t) {
        // ---- stage x fragments (entries 16*64 .. 20*64) — off critical path ----
        if (tid < 256) {
            const int kk = tid >> 6;              // 0..3
            const int ln = tid & 63;
            const int n  = ln & 15;
            const int k0 = kk * 32 + (ln >> 4) * 8;
            const float* xp = x + ((size_t)(g * GB + n) * T_ + t) * D_ + k0;
            short8 v;
            #pragma unroll
            for (int j = 0; j < 8; ++j) v[j] = (short)f2bf(xp[j]);
            *(short8*)&Bstage[(16 * 64 + tid) * 8] = v;
        }

        // ---- poll: all threads spin on the group's arrival counter ----
        if (t > 0) {
            while (__hip_atomic_load(&arrive[t * 8 + g], __ATOMIC_RELAXED,
                                     __HIP_MEMORY_SCOPE_AGENT) < NS) {}
        }
        __asm__ __volatile__("" ::: "memory");

        // ---- stage h fragments via relaxed agent u32 loads (coherence point) ----
        {
            const unsigned int* hsrc = h_buf + (size_t)(t & 1) * (B_ * H_ / 2);
            #pragma unroll
            for (int e = 0; e < 2; ++e) {
                const int c  = tid + e * 512;     // 0..1023
                const int kk = c >> 6;
                const int ln = c & 63;
                const int n  = ln & 15;
                const int k0 = kk * 32 + (ln >> 4) * 8;
                unsigned int* sp = (unsigned int*)(hsrc + ((size_t)(g * GB + n) * H_ + k0) / 2);
                union { unsigned int u[4]; short8 v; } r;
                #pragma unroll
                for (int j2 = 0; j2 < 4; ++j2)
                    r.u[j2] = __hip_atomic_load(sp + j2, __ATOMIC_RELAXED,
                                                __HIP_MEMORY_SCOPE_AGENT);
                *(short8*)&Bstage[c * 8] = r.v;
            }
        }
        __syncthreads();

        // ---- MFMA, K=640, two independent accumulator chains ----
        f32x4 acc0 = {0.f, 0.f, 0.f, 0.f}, acc1 = {0.f, 0.f, 0.f, 0.f};
        #pragma unroll
        for (int kk = 0; kk < NKK; kk += 2) {
            const short8 b0 = *(const short8*)&Bstage[(kk * 64 + lane) * 8];
            const short8 b1 = *(const short8*)&Bstage[((kk + 1) * 64 + lane) * 8];
            acc0 = __builtin_amdgcn_mfma_f32_16x16x32_bf16(wfrag[kk], b0, acc0, 0, 0, 0);
            acc1 = __builtin_amdgcn_mfma_f32_16x16x32_bf16(wfrag[kk + 1], b1, acc1, 0, 0, 0);
        }
        {
            const int col  = lane & 15;
            const int quad = lane >> 4;
            #pragma unroll
            for (int rr = 0; rr < 4; ++rr)
                gate_lds[q][half * 16 + quad * 4 + rr][col] = acc0[rr] + acc1[rr];
        }
        __syncthreads();

        // ---- elementwise cell (fp32 c in registers) ----
        {
            const float gi = gate_lds[0][e_hu][e_n] + bi;
            const float gf = gate_lds[1][e_hu][e_n] + bf;
            const float gg = gate_lds[2][e_hu][e_n] + bg;
            const float go = gate_lds[3][e_hu][e_n] + bo;
            const float h = fast_sig(go) *
                            (c_val = fast_sig(gf) * c_val + fast_sig(gi) * fast_tanh(gg),
                             fast_tanh(c_val));
            // pack bf16 pair across quads (lane, lane+16 share e_n, adjacent e_hu)
            const float h_hi = __shfl_down(h, 16, 64);
            if (((tid >> 4) & 1) == 0) {
                const unsigned int val = (unsigned int)f2bf(h) |
                                         ((unsigned int)f2bf(h_hi) << 16);
                unsigned int* hdst = h_buf + (size_t)((t + 1) & 1) * (B_ * H_ / 2)
                                   + ((size_t)bb * H_ + hu_g) / 2;
                __hip_atomic_store(hdst, val, __ATOMIC_RELAXED,
                                   __HIP_MEMORY_SCOPE_AGENT);
            }
            if (t == T_ - 1) hfin[(size_t)bb * H_ + hu_g] = h;
        }
        __syncthreads();   // drains vmcnt(0): h stores at coherence point

        // ---- publish (relaxed: ordering provided by the waitcnt above) ----
        if (tid == 0)
            __hip_atomic_fetch_add(&arrive[(t + 1) * 8 + g], 1u, __ATOMIC_RELAXED,
                                   __HIP_MEMORY_SCOPE_AGENT);
    }
}

// Head: logits = h_final @ W_out^T, softmax. One wave per batch row.
__global__ void head_kernel(const float* __restrict__ hfin,
                            const float* __restrict__ W_out,
                            float* __restrict__ out)
{
    const int bidx = blockIdx.x;
    const int l    = threadIdx.x;      // 0..63
    float hv[8];
    #pragma unroll
    for (int j = 0; j < 8; ++j) hv[j] = hfin[bidx * 512 + j * 64 + l];
    __shared__ float logits[L_];
    for (int o = 0; o < L_; ++o) {
        float p = 0.f;
        #pragma unroll
        for (int j = 0; j < 8; ++j) p += hv[j] * W_out[o * 512 + j * 64 + l];
        #pragma unroll
        for (int off = 32; off; off >>= 1) p += __shfl_down(p, off, 64);
        if (l == 0) logits[o] = p;
    }
    __syncthreads();
    if (l == 0) {
        float mx = logits[0];
        for (int o = 1; o < L_; ++o) mx = fmaxf(mx, logits[o]);
        float e[L_], sum = 0.f;
        for (int o = 0; o < L_; ++o) { e[o] = __expf(logits[o] - mx); sum += e[o]; }
        const float inv = 1.f / sum;
        for (int o = 0; o < L_; ++o) out[bidx * L_ + o] = e[o] * inv;
    }
}

extern "C" void kernel_launch(void* const* d_in, const int* in_sizes, int n_in,
                              void* d_out, int out_size, void* d_ws, size_t ws_size,
                              hipStream_t stream) {
    const float* x     = (const float*)d_in[0];
    const float* W_ih  = (const float*)d_in[1];
    const float* W_hh  = (const float*)d_in[2];
    const float* bias  = (const float*)d_in[3];
    const float* W_out = (const float*)d_in[4];
    float* out = (float*)d_out;

    // ws: h_buf [2][128][512] bf16 (262144 B) | arrive [2049][8] u32 (65792 B
    // padded) | hfin [128][512] f32 (262144 B)
    char* ws = (char*)d_ws;
    unsigned int* h_buf  = (unsigned int*)ws;
    unsigned int* arrive = (unsigned int*)(ws + 262144);
    float*        hfin   = (float*)(ws + 262144 + 65792);

    hipMemsetAsync(ws, 0, 262144 + 65792, stream);

    void* args[] = { (void*)&x, (void*)&W_ih, (void*)&W_hh, (void*)&bias,
                     (void*)&h_buf, (void*)&arrive, (void*)&hfin };
    hipLaunchCooperativeKernel((void*)lstm_kernel, dim3(NG * NS), dim3(512),
                               args, 0, stream);
    head_kernel<<<dim3(B_), dim3(64), 0, stream>>>(hfin, W_out, out);
}